// Round 8
// baseline (83.917 us; speedup 1.0000x reference)
//
#include <hip/hip_runtime.h>
#include <hip/hip_bf16.h>
#include <cstdint>

#define KD 512
#define BM 64
#define NT 256
#define NSPLIT 63
#define NNODES 127

typedef __attribute__((ext_vector_type(8))) short bf16x8;
typedef __attribute__((ext_vector_type(4))) float f32x4;

#define MFMA_B16(a, b, c) __builtin_amdgcn_mfma_f32_16x16x32_bf16(a, b, c, 0, 0, 0)

static __device__ __forceinline__ unsigned short f2bf(float f) {
    return __builtin_bit_cast(unsigned short, __float2bfloat16(f));
}
static __device__ __forceinline__ float bf2f(unsigned short h) {
    return __builtin_bit_cast(float, (unsigned)h << 16);
}
static __device__ __forceinline__ unsigned pack2(float f0, float f1) {
    return (unsigned)f2bf(f0) | ((unsigned)f2bf(f1) << 16);
}

// 8 fp32 -> bf16 hi8 + residual lo8; named scalars only (stays in VGPRs)
static __device__ __forceinline__ void cvt8(f32x4 a, f32x4 b, bf16x8& hi, bf16x8& lo) {
    const unsigned short h0 = f2bf(a[0]), h1 = f2bf(a[1]), h2 = f2bf(a[2]), h3 = f2bf(a[3]);
    const unsigned short h4 = f2bf(b[0]), h5 = f2bf(b[1]), h6 = f2bf(b[2]), h7 = f2bf(b[3]);
    uint4 H = make_uint4((unsigned)h0 | ((unsigned)h1 << 16), (unsigned)h2 | ((unsigned)h3 << 16),
                         (unsigned)h4 | ((unsigned)h5 << 16), (unsigned)h6 | ((unsigned)h7 << 16));
    uint4 L = make_uint4(pack2(a[0] - bf2f(h0), a[1] - bf2f(h1)),
                         pack2(a[2] - bf2f(h2), a[3] - bf2f(h3)),
                         pack2(b[0] - bf2f(h4), b[1] - bf2f(h5)),
                         pack2(b[2] - bf2f(h6), b[3] - bf2f(h7)));
    hi = __builtin_bit_cast(bf16x8, H);
    lo = __builtin_bit_cast(bf16x8, L);
}

static __device__ __forceinline__ void gload_lds16(const float* g, void* l) {
    __builtin_amdgcn_global_load_lds(
        (const __attribute__((address_space(1))) unsigned int*)g,
        (__attribute__((address_space(3))) unsigned int*)l, 16, 0, 0);
}

template<int N> static __device__ __forceinline__ void vmwait() {
    if constexpr (N == 2) asm volatile("s_waitcnt vmcnt(2)" ::: "memory");
    else                  asm volatile("s_waitcnt vmcnt(0)" ::: "memory");
}

// DFS path-min walk; lane `part` stores clipped nodes [part*32, part*32+32)
template<int T>
static __device__ __forceinline__ void tree_walk(float qt, const float* __restrict__ srow,
                                                 float* __restrict__ zrow, int part) {
    const float s  = srow[T];
    const float ql = fminf(qt, s);
    const float qr = fminf(qt, -s);
    if (((2 * T + 1) >> 5) == part) zrow[2 * T + 1] = fminf(fmaxf(ql, 0.f), 1.f);
    if (((2 * T + 2) >> 5) == part) zrow[2 * T + 2] = fminf(fmaxf(qr, 0.f), 1.f);
    if constexpr (2 * T + 1 < NSPLIT) tree_walk<2 * T + 1>(ql, srow, zrow, part);
    if constexpr (2 * T + 2 < NSPLIT) tree_walk<2 * T + 2>(qr, srow, zrow, part);
}

// write B chunk (64 rows x 32 k) bf16 hi/lo from regs; slot-swizzled b128 writes
static __device__ __forceinline__ void write_B(unsigned char* ldsb, int wb_off,
                                               bool bvalid, f32x4 b0, f32x4 b1) {
    if (!bvalid) { b0 = (f32x4)(0.f); b1 = (f32x4)(0.f); }
    bf16x8 hi, lo;
    cvt8(b0, b1, hi, lo);
    *reinterpret_cast<bf16x8*>(ldsb + 8192 + wb_off)  = hi;
    *reinterpret_cast<bf16x8*>(ldsb + 12288 + wb_off) = lo;
}

struct Ctx {
    const float* xsrc;       // per-lane global x source (tile 0)
    const float* ag;         // per-thread A source (chunk 0)
    unsigned char* xbf;      // wave-private x LDS buf (2 KB)
    unsigned char* ldsb;     // block LDS base
    int va_off;              // byte offset of va fragment in xbf
    int bo;                  // byte offset of B fragment base (in hi plane)
    int wb_off;              // byte offset of B write slot
    bool bvalid;
};

// one k=32 step, fully compile-time; single-buffered x, sbuf B chunk per step
template<int T>
static __device__ __forceinline__ void tiles(const Ctx& c, f32x4 (&acc)[4],
                                             f32x4& bn0, f32x4& bn1) {
    vmwait<(T == 15) ? 0 : 2>();                 // x tile T resident (own-wave DMA)
    __builtin_amdgcn_sched_barrier(0);
    f32x4 va = *reinterpret_cast<const f32x4*>(c.xbf + c.va_off);
    f32x4 vb = *reinterpret_cast<const f32x4*>(c.xbf + (c.va_off ^ 16));
    asm volatile("s_waitcnt lgkmcnt(0)" ::: "memory");   // frags in regs
    __builtin_amdgcn_sched_barrier(0);
    if constexpr (T + 1 < 16) {                  // refill same buf (in-wave safe now)
        gload_lds16(c.xsrc + (T + 1) * 32, c.xbf);
        gload_lds16(c.xsrc + (T + 1) * 32 + 8 * KD, c.xbf + 1024);
    }
    __builtin_amdgcn_sched_barrier(0);

    bf16x8 ah, al;
    cvt8(va, vb, ah, al);
    const unsigned char* bh = c.ldsb + 8192 + c.bo;
#pragma unroll
    for (int nf = 0; nf < 4; ++nf) {             // 2 live B-frags max (VGPR cap)
        const bf16x8 bhv = *reinterpret_cast<const bf16x8*>(bh + nf * 1024);
        const bf16x8 blv = *reinterpret_cast<const bf16x8*>(bh + 4096 + nf * 1024);
        acc[nf] = MFMA_B16(ah, bhv, acc[nf]);
        acc[nf] = MFMA_B16(al, bhv, acc[nf]);
        acc[nf] = MFMA_B16(ah, blv, acc[nf]);
    }

    if constexpr (T + 1 < 16) {
        __builtin_amdgcn_sched_barrier(0);
        __builtin_amdgcn_s_barrier();            // all waves done reading chunk T
        write_B(c.ldsb, c.wb_off, c.bvalid, bn0, bn1);   // chunk T+1 (vmcnt by compiler)
        asm volatile("s_waitcnt lgkmcnt(0)" ::: "memory");
        __builtin_amdgcn_s_barrier();            // chunk T+1 visible
        __builtin_amdgcn_sched_barrier(0);
        if constexpr (T + 2 < 16) {
            if (c.bvalid) {
                bn0 = *reinterpret_cast<const f32x4*>(c.ag + (T + 2) * 32);
                bn1 = *reinterpret_cast<const f32x4*>(c.ag + (T + 2) * 32 + 4);
            }
        }
        tiles<T + 1>(c, acc, bn0, bn1);
    }
}

// LDS (16384 B): x wave bufs [0,8K); B hi [8K,12K); B lo [12K,16K).
// Epilogue (after sync): one wave at a time uses [0,12288): warea[16][65] + zw[16*127].
__global__ __launch_bounds__(NT, 8)
void lt_mfma7(const float* __restrict__ x, const float* __restrict__ A,
              float* __restrict__ out) {
    __shared__ __align__(16) unsigned char lds[16384];

    const int tid  = threadIdx.x;
    const int wave = tid >> 6;
    const int lane = tid & 63;
    const int fr   = lane & 15;
    const int g    = lane >> 4;
    const int r0   = blockIdx.x * BM;

    Ctx c;
    c.ldsb  = lds;
    c.xbf   = lds + wave * 2048;
    c.xsrc  = x + (size_t)(r0 + wave * 16 + (lane >> 3)) * KD
                + (((lane & 7) ^ (lane >> 3)) << 2);
    const int brow = tid >> 2;
    const int q    = tid & 3;
    c.ag     = A + (size_t)brow * KD + q * 8;
    c.bvalid = brow < NSPLIT;
    c.wb_off = (brow << 6) + ((q ^ (brow & 3)) << 4);
    c.va_off = (fr << 7) + (((g << 1) ^ (fr & 7)) << 4);
    c.bo     = (fr << 6) + ((g ^ (fr & 3)) << 4);

    f32x4 acc[4];
#pragma unroll
    for (int j = 0; j < 4; ++j) acc[j] = (f32x4)(0.f);

    // prologue: B chunk-0 regs, x tile-0 DMA, write chunk 0, barrier, chunk-1 regs
    f32x4 bn0 = (f32x4)(0.f), bn1 = (f32x4)(0.f);
    if (c.bvalid) {
        bn0 = *reinterpret_cast<const f32x4*>(c.ag);
        bn1 = *reinterpret_cast<const f32x4*>(c.ag + 4);
    }
    gload_lds16(c.xsrc, c.xbf);
    gload_lds16(c.xsrc + 8 * KD, c.xbf + 1024);
    write_B(c.ldsb, c.wb_off, c.bvalid, bn0, bn1);       // vmcnt(2): x DMA keeps flying
    asm volatile("s_waitcnt lgkmcnt(0)" ::: "memory");
    __builtin_amdgcn_s_barrier();
    if (c.bvalid) {
        bn0 = *reinterpret_cast<const f32x4*>(c.ag + 32);
        bn1 = *reinterpret_cast<const f32x4*>(c.ag + 36);
    }

    tiles<0>(c, acc, bn0, bn1);

    __syncthreads();                             // K-loop LDS free for epilogue

    // ---- epilogue: waves time-share 12.3 KB; warea[16][65] + zw[16*127]
    float* warea = reinterpret_cast<float*>(lds);
    float* zw    = warea + 1040;
    const int o    = lane >> 2;                  // row 0..15
    const int part = lane & 3;                   // nodes [part*32, part*32+32)

#pragma unroll
    for (int ph = 0; ph < 4; ++ph) {
        if (wave == ph) {
#pragma unroll
            for (int nf = 0; nf < 4; ++nf)
#pragma unroll
                for (int rg = 0; rg < 4; ++rg)
                    warea[(4 * g + rg) * 65 + nf * 16 + fr] = acc[nf][rg];
            // same-wave LDS ordering via lgkm; no barrier needed inside
            const float* srow = warea + o * 65;
            float* zrow = zw + o * NNODES;
            if (part == 0) zrow[0] = 1.f;
            tree_walk<0>(1.f, srow, zrow, part);

            float* og = out + (size_t)(r0 + wave * 16) * NNODES;
#pragma unroll
            for (int j = 0; j < 8; ++j) {
                const int idx = j * 64 + lane;
                if (idx < 508)
                    *reinterpret_cast<f32x4*>(og + idx * 4) =
                        *reinterpret_cast<const f32x4*>(zw + idx * 4);
            }
        }
        __syncthreads();
    }
}

extern "C" void kernel_launch(void* const* d_in, const int* in_sizes, int n_in,
                              void* d_out, int out_size, void* d_ws, size_t ws_size,
                              hipStream_t stream) {
    const float* x = (const float*)d_in[0];   // [131072, 512]
    const float* A = (const float*)d_in[1];   // [63, 512]
    float* out = (float*)d_out;               // [131072, 127]
    const int nrows = in_sizes[0] / KD;       // 131072
    const int grid = nrows / BM;              // 2048 blocks = 8/CU, all resident
    lt_mfma7<<<dim3(grid), dim3(NT), 0, stream>>>(x, A, out);
}